// Round 1
// baseline (333.970 us; speedup 1.0000x reference)
//
#include <hip/hip_runtime.h>

#define B     256
#define NPIX  49152
#define NRET  3072
#define NV1   6144
#define NIT   3072
#define NCLS  1000

#define CC      8            // classes per block in classifier
#define SPLITK  8
#define KCH     (NIT / SPLITK)   // 384

__device__ __forceinline__ float sigmoidf_(float v) {
    return 1.0f / (1.0f + __expf(-v));
}

// ---------------- Retina + LGN fused ----------------
// grid: (NRET/256, B), block 256. Thread t handles neuron n = bx*256+t for batch by.
// Writes r2 in [B][NRET] layout (coalesced).
__global__ __launch_bounds__(256) void k_retina(
    const float* __restrict__ x, const float* __restrict__ w_ret,
    const float* __restrict__ b_ret, const float* __restrict__ w_lgn,
    const float* __restrict__ b_lgn, const int* __restrict__ pixel_map,
    float* __restrict__ r2)
{
    int b = blockIdx.y;
    int n = blockIdx.x * 256 + threadIdx.x;
    const float* xb = x + (size_t)b * NPIX;
    const int4*   pm4 = (const int4*)(pixel_map + n * 16);
    const float4* wr4 = (const float4*)(w_ret + n * 16);
    const float4* wl4 = (const float4*)(w_lgn + n * 16);
    float dot = 0.f, sl = 0.f;
#pragma unroll
    for (int q = 0; q < 4; ++q) {
        int4 p = pm4[q];
        float4 w = wr4[q];
        dot += xb[p.x] * w.x + xb[p.y] * w.y + xb[p.z] * w.z + xb[p.w] * w.w;
        float4 l = wl4[q];
        sl += l.x + l.y + l.z + l.w;
    }
    float r1 = sigmoidf_(dot - b_ret[n]);
    r2[(size_t)b * NRET + n] = sigmoidf_(r1 * sl - b_lgn[n]);
}

// ---------------- Transpose [B][NRET] -> [NRET][B] ----------------
__global__ __launch_bounds__(256) void k_transpose(
    const float* __restrict__ in, float* __restrict__ out)
{
    __shared__ float tile[32][33];           // +1 pad: conflict-free
    int tx = threadIdx.x & 31, ty = threadIdx.x >> 5;   // ty 0..7
    int n0 = blockIdx.x * 32, b0 = blockIdx.y * 32;
#pragma unroll
    for (int i = 0; i < 4; ++i)
        tile[ty + i * 8][tx] = in[(size_t)(b0 + ty + i * 8) * NRET + n0 + tx];
    __syncthreads();
#pragma unroll
    for (int i = 0; i < 4; ++i)
        out[(size_t)(n0 + ty + i * 8) * B + b0 + tx] = tile[tx][ty + i * 8];
}

// ---------------- Sparse mean layer (V1 / IT) ----------------
// One workgroup per output neuron j. 256 threads = 256 batches.
// Scan mask row -> compact nonzero indices in LDS (count == rowsum since binary),
// then gather coalesced 1KB rows from act_t (L2-resident).
template<int K>
__global__ __launch_bounds__(256) void k_sparse(
    const float* __restrict__ act_t,   // [K][B]
    const int*   __restrict__ mask,    // [njp][K]
    const float* __restrict__ w,       // [njp][32]
    const float* __restrict__ bias,    // [njp]
    float*       __restrict__ out_t)   // [njp][B]
{
    __shared__ int   idxs[1024];
    __shared__ int   cnt;
    __shared__ float wrow[32];
    int j = blockIdx.x;
    int t = threadIdx.x;
    if (t == 0) cnt = 0;
    if (t < 32) wrow[t] = w[j * 32 + t];
    __syncthreads();

    const int4* row4 = (const int4*)(mask + (size_t)j * K);
    for (int q = t; q < K / 4; q += 256) {
        int4 m = row4[q];
        int base = q * 4;
        if (m.x) { int p = atomicAdd(&cnt, 1); if (p < 1024) idxs[p] = base;     }
        if (m.y) { int p = atomicAdd(&cnt, 1); if (p < 1024) idxs[p] = base + 1; }
        if (m.z) { int p = atomicAdd(&cnt, 1); if (p < 1024) idxs[p] = base + 2; }
        if (m.w) { int p = atomicAdd(&cnt, 1); if (p < 1024) idxs[p] = base + 3; }
    }
    __syncthreads();

    int n = cnt < 1024 ? cnt : 1024;
    float acc = 0.f;
    for (int i = 0; i < n; ++i)
        acc += act_t[(size_t)idxs[i] * B + t];   // coalesced 1KB, L2-hit

    float sw = 0.f;
#pragma unroll
    for (int i = 0; i < 32; ++i) sw += wrow[i];  // broadcast reads, conflict-free

    float v = acc / (float)n * sw - bias[j];
    out_t[(size_t)j * B + t] = sigmoidf_(v);
}

// ---------------- Classifier: partial GEMM (split-K, no atomics) ----------------
// grid (NCLS/CC, SPLITK). Thread t = batch. Stages W tile in LDS (broadcast reads).
__global__ __launch_bounds__(256) void k_cls(
    const float* __restrict__ r4t,   // [NIT][B]
    const float* __restrict__ W,     // [NCLS][NIT]
    float*       __restrict__ part)  // [SPLITK][B][NCLS]
{
    __shared__ float wl[CC * KCH];   // 12 KB
    int c0 = blockIdx.x * CC;
    int ky = blockIdx.y;
    int k0 = ky * KCH;
    int t  = threadIdx.x;
#pragma unroll
    for (int c = 0; c < CC; ++c)
        for (int kk = t; kk < KCH; kk += 256)
            wl[c * KCH + kk] = W[(size_t)(c0 + c) * NIT + k0 + kk];
    __syncthreads();

    float acc[CC];
#pragma unroll
    for (int c = 0; c < CC; ++c) acc[c] = 0.f;

    const float4* wl4 = (const float4*)wl;
    for (int kk = 0; kk < KCH; kk += 4) {
        float4 r;
        r.x = r4t[(size_t)(k0 + kk    ) * B + t];
        r.y = r4t[(size_t)(k0 + kk + 1) * B + t];
        r.z = r4t[(size_t)(k0 + kk + 2) * B + t];
        r.w = r4t[(size_t)(k0 + kk + 3) * B + t];
#pragma unroll
        for (int c = 0; c < CC; ++c) {
            float4 w = wl4[(c * KCH + kk) >> 2];
            acc[c] += r.x * w.x + r.y * w.y + r.z * w.z + r.w * w.w;
        }
    }
    // 32B per thread, 16B-aligned (1000 and c0 are multiples of 4 floats)
    float* dst = part + (size_t)ky * (B * NCLS) + (size_t)t * NCLS + c0;
#pragma unroll
    for (int c = 0; c < CC; ++c) dst[c] = acc[c];
}

__global__ __launch_bounds__(256) void k_cls_reduce(
    const float* __restrict__ part, const float* __restrict__ b_cls,
    float* __restrict__ out)
{
    int i = blockIdx.x * 256 + threadIdx.x;   // i < B*NCLS (exact multiple)
    float s = b_cls[i % NCLS];
#pragma unroll
    for (int p = 0; p < SPLITK; ++p) s += part[(size_t)p * (B * NCLS) + i];
    out[i] = s;
}

extern "C" void kernel_launch(void* const* d_in, const int* in_sizes, int n_in,
                              void* d_out, int out_size, void* d_ws, size_t ws_size,
                              hipStream_t stream) {
    const float* x      = (const float*)d_in[0];
    const float* w_ret  = (const float*)d_in[1];
    const float* b_ret  = (const float*)d_in[2];
    const float* w_lgn  = (const float*)d_in[3];
    const float* b_lgn  = (const float*)d_in[4];
    const float* w_v1   = (const float*)d_in[5];
    const float* b_v1   = (const float*)d_in[6];
    const float* w_it   = (const float*)d_in[7];
    const float* b_it   = (const float*)d_in[8];
    const float* W_cls  = (const float*)d_in[9];
    const float* b_cls  = (const float*)d_in[10];
    const int*   pixmap = (const int*)d_in[11];
    const int*   m1     = (const int*)d_in[12];
    const int*   m2     = (const int*)d_in[13];
    float* out = (float*)d_out;

    float* ws  = (float*)d_ws;
    float* r2   = ws;                                  // [B][NRET]     786432
    float* r2t  = r2  + (size_t)B * NRET;              // [NRET][B]     786432
    float* r3t  = r2t + (size_t)NRET * B;              // [NV1][B]     1572864
    float* r4t  = r3t + (size_t)NV1 * B;               // [NIT][B]      786432
    float* part = r4t + (size_t)NIT * B;               // [SPLITK][B][NCLS] 2048000

    k_retina<<<dim3(NRET / 256, B), 256, 0, stream>>>(x, w_ret, b_ret, w_lgn, b_lgn, pixmap, r2);
    k_transpose<<<dim3(NRET / 32, B / 32), 256, 0, stream>>>(r2, r2t);
    k_sparse<NRET><<<NV1, 256, 0, stream>>>(r2t, m1, w_v1, b_v1, r3t);
    k_sparse<NV1><<<NIT, 256, 0, stream>>>(r3t, m2, w_it, b_it, r4t);
    k_cls<<<dim3(NCLS / CC, SPLITK), 256, 0, stream>>>(r4t, W_cls, part);
    k_cls_reduce<<<(B * NCLS) / 256, 256, 0, stream>>>(part, b_cls, out);
}

// Round 2
// 301.895 us; speedup vs baseline: 1.1062x; 1.1062x over previous
//
#include <hip/hip_runtime.h>

#define B     256
#define NPIX  49152
#define NRET  3072
#define NV1   6144
#define NIT   3072
#define NCLS  1000

typedef unsigned short ushort_t;
typedef __bf16 bf16x8 __attribute__((ext_vector_type(8)));
typedef float  f32x4  __attribute__((ext_vector_type(4)));

__device__ __forceinline__ float sigmoidf_(float v) {
    return 1.0f / (1.0f + __expf(-v));
}

__device__ __forceinline__ ushort_t f2bf(float f) {
    union { float f; unsigned u; } v; v.f = f;
    unsigned r = (v.u + 0x7fffu + ((v.u >> 16) & 1u)) >> 16;
    return (ushort_t)r;
}

// ---------------- Retina + LGN fused, writes TRANSPOSED [NRET][B] ----------------
// grid (NRET/32, B/32), block 256. 32x32 tile, LDS transpose for coalesced store.
__global__ __launch_bounds__(256) void k_retina_t(
    const float* __restrict__ x, const float* __restrict__ w_ret,
    const float* __restrict__ b_ret, const float* __restrict__ w_lgn,
    const float* __restrict__ b_lgn, const int* __restrict__ pixel_map,
    float* __restrict__ r2t)
{
    __shared__ float tile[32][33];
    int tx = threadIdx.x & 31, ty = threadIdx.x >> 5;
    int n0 = blockIdx.x * 32, b0 = blockIdx.y * 32;
    int n = n0 + tx;
    const int4*   pm4 = (const int4*)(pixel_map + n * 16);
    const float4* wr4 = (const float4*)(w_ret + n * 16);
    const float4* wl4 = (const float4*)(w_lgn + n * 16);
    int4 p[4]; float4 wr[4]; float slw = 0.f;
#pragma unroll
    for (int q = 0; q < 4; ++q) {
        p[q] = pm4[q]; wr[q] = wr4[q];
        float4 L = wl4[q]; slw += L.x + L.y + L.z + L.w;
    }
    float br = b_ret[n], bl = b_lgn[n];
#pragma unroll
    for (int i = 0; i < 4; ++i) {
        int b = b0 + ty + i * 8;
        const float* xb = x + (size_t)b * NPIX;
        float dot = 0.f;
#pragma unroll
        for (int q = 0; q < 4; ++q)
            dot += xb[p[q].x] * wr[q].x + xb[p[q].y] * wr[q].y
                 + xb[p[q].z] * wr[q].z + xb[p[q].w] * wr[q].w;
        float r1 = sigmoidf_(dot - br);
        tile[ty + i * 8][tx] = sigmoidf_(r1 * slw - bl);
    }
    __syncthreads();
#pragma unroll
    for (int i = 0; i < 4; ++i)
        r2t[(size_t)(n0 + ty + i * 8) * B + b0 + tx] = tile[tx][ty + i * 8];
}

// ---------------- Sparse mean layer: ONE WAVE per neuron, float4 per lane ----------
// block 256 = 4 waves = 4 neurons. Lane l covers batches 4l..4l+3 (dwordx4, 1KB/wave).
template<int K, bool OUT_BF16>
__global__ __launch_bounds__(256) void k_sparse(
    const float* __restrict__ act_t,   // [K][B]
    const int*   __restrict__ mask,    // [NJ][K]
    const float* __restrict__ w,       // [NJ][32]
    const float* __restrict__ bias,    // [NJ]
    void*        __restrict__ out_t)   // [NJ][B] f32 or bf16
{
    constexpr int MAXI = 192;
    __shared__ int idxs[4][MAXI];
    __shared__ int cnts[4];
    int t = threadIdx.x, wv = t >> 6, l = t & 63;
    int j = blockIdx.x * 4 + wv;
    if (l == 0) cnts[wv] = 0;
    // per-wave LDS: in-order within wave, no cross-wave sharing -> no __syncthreads

    const int4* row4 = (const int4*)(mask + (size_t)j * K);
#pragma unroll
    for (int q = l; q < K / 4; q += 64) {
        int4 m = row4[q];
        int base = q * 4;
        if (m.x) { int p = atomicAdd(&cnts[wv], 1); if (p < MAXI) idxs[wv][p] = base;     }
        if (m.y) { int p = atomicAdd(&cnts[wv], 1); if (p < MAXI) idxs[wv][p] = base + 1; }
        if (m.z) { int p = atomicAdd(&cnts[wv], 1); if (p < MAXI) idxs[wv][p] = base + 2; }
        if (m.w) { int p = atomicAdd(&cnts[wv], 1); if (p < MAXI) idxs[wv][p] = base + 3; }
    }
    int n = cnts[wv];
    if (n > MAXI) n = MAXI;

    const float4* a4 = (const float4*)act_t;     // [K][64] float4 view
    float4 acc0 = {0,0,0,0}, acc1 = {0,0,0,0};
    int i = 0;
    for (; i + 2 <= n; i += 2) {
        int j0 = idxs[wv][i], j1 = idxs[wv][i + 1];
        float4 v0 = a4[(size_t)j0 * 64 + l];
        float4 v1 = a4[(size_t)j1 * 64 + l];
        acc0.x += v0.x; acc0.y += v0.y; acc0.z += v0.z; acc0.w += v0.w;
        acc1.x += v1.x; acc1.y += v1.y; acc1.z += v1.z; acc1.w += v1.w;
    }
    if (i < n) {
        float4 v0 = a4[(size_t)idxs[wv][i] * 64 + l];
        acc0.x += v0.x; acc0.y += v0.y; acc0.z += v0.z; acc0.w += v0.w;
    }
    acc0.x += acc1.x; acc0.y += acc1.y; acc0.z += acc1.z; acc0.w += acc1.w;

    float sw = w[(size_t)j * 32 + (l & 31)];
#pragma unroll
    for (int off = 1; off < 32; off <<= 1) sw += __shfl_xor(sw, off);

    float bj = bias[j];
    float scale = sw / (float)n;
    float o0 = sigmoidf_(acc0.x * scale - bj);
    float o1 = sigmoidf_(acc0.y * scale - bj);
    float o2 = sigmoidf_(acc0.z * scale - bj);
    float o3 = sigmoidf_(acc0.w * scale - bj);

    if (OUT_BF16) {
        ushort_t* dst = (ushort_t*)out_t + (size_t)j * B + l * 4;
        ushort4 o; o.x = f2bf(o0); o.y = f2bf(o1); o.z = f2bf(o2); o.w = f2bf(o3);
        *(ushort4*)dst = o;
    } else {
        float4* dst = (float4*)((float*)out_t + (size_t)j * B + l * 4);
        float4 o; o.x = o0; o.y = o1; o.z = o2; o.w = o3;
        *dst = o;
    }
}

// ---------------- Prep: W_cls fp32 -> bf16 (padded to 1024 rows) + r4 transpose ----
// blocks [0,1536): convert W (8 elems/thread). blocks [1536,2304): transpose r4.
__global__ __launch_bounds__(256) void k_prep(
    const float* __restrict__ W,           // [1000][3072]
    const ushort_t* __restrict__ r4bt,     // [NIT][B] bf16
    ushort_t* __restrict__ wbf,            // [1024][3072] bf16, rows>=1000 zero
    ushort_t* __restrict__ r4b)            // [B][NIT] bf16
{
    __shared__ ushort_t stile[32][33];
    int bx = blockIdx.x, t = threadIdx.x;
    if (bx < 1536) {
        int e = (bx * 256 + t) * 8;        // flat over 1024*3072
        uint4 o = {0, 0, 0, 0};
        if (e < NCLS * NIT) {
            float4 f0 = *(const float4*)(W + e);
            float4 f1 = *(const float4*)(W + e + 4);
            o.x = (unsigned)f2bf(f0.x) | ((unsigned)f2bf(f0.y) << 16);
            o.y = (unsigned)f2bf(f0.z) | ((unsigned)f2bf(f0.w) << 16);
            o.z = (unsigned)f2bf(f1.x) | ((unsigned)f2bf(f1.y) << 16);
            o.w = (unsigned)f2bf(f1.z) | ((unsigned)f2bf(f1.w) << 16);
        }
        *(uint4*)(wbf + e) = o;
    } else {
        int tb = bx - 1536;                // 96 n-tiles x 8 b-tiles
        int tn = tb / 8, tbb = tb % 8;
        int tx = t & 31, ty = t >> 5;
#pragma unroll
        for (int i = 0; i < 4; ++i)
            stile[ty + i * 8][tx] = r4bt[(size_t)(tn * 32 + ty + i * 8) * B + tbb * 32 + tx];
        __syncthreads();
#pragma unroll
        for (int i = 0; i < 4; ++i)
            r4b[(size_t)(tbb * 32 + ty + i * 8) * NIT + tn * 32 + tx] = stile[tx][ty + i * 8];
    }
}

// ---------------- Classifier: bf16 MFMA, split-K=4, fp32 partials ----------------
// grid (16 cblk, 4 bblk, 4 kz), block 256 = 4 waves. Wave: 16b x 64c, K-chunk 768.
__global__ __launch_bounds__(256) void k_cls_mfma(
    const ushort_t* __restrict__ r4b,   // [256][3072] bf16
    const ushort_t* __restrict__ wbf,   // [1024][3072] bf16
    float* __restrict__ part)           // [4][256][1000]
{
    int t = threadIdx.x, wv = t >> 6, l = t & 63;
    int cb = blockIdx.x, bb = blockIdx.y, kz = blockIdx.z;
    int m = l & 15, quad = l >> 4;
    int brow = bb * 64 + wv * 16 + m;
    const bf16x8* pa = (const bf16x8*)(r4b + (size_t)brow * NIT + kz * 768 + quad * 8);
    const bf16x8* pb0 = (const bf16x8*)(wbf + (size_t)(cb * 64 +  0 + m) * NIT + kz * 768 + quad * 8);
    const bf16x8* pb1 = (const bf16x8*)(wbf + (size_t)(cb * 64 + 16 + m) * NIT + kz * 768 + quad * 8);
    const bf16x8* pb2 = (const bf16x8*)(wbf + (size_t)(cb * 64 + 32 + m) * NIT + kz * 768 + quad * 8);
    const bf16x8* pb3 = (const bf16x8*)(wbf + (size_t)(cb * 64 + 48 + m) * NIT + kz * 768 + quad * 8);

    f32x4 acc0 = {0,0,0,0}, acc1 = {0,0,0,0}, acc2 = {0,0,0,0}, acc3 = {0,0,0,0};
#pragma unroll 4
    for (int s = 0; s < 24; ++s) {      // 24 steps x 32 k = 768
        bf16x8 a  = pa [s * 4];          // 4 bf16x8 units per 32-k step
        bf16x8 b0 = pb0[s * 4];
        bf16x8 b1 = pb1[s * 4];
        bf16x8 b2 = pb2[s * 4];
        bf16x8 b3 = pb3[s * 4];
        acc0 = __builtin_amdgcn_mfma_f32_16x16x32_bf16(a, b0, acc0, 0, 0, 0);
        acc1 = __builtin_amdgcn_mfma_f32_16x16x32_bf16(a, b1, acc1, 0, 0, 0);
        acc2 = __builtin_amdgcn_mfma_f32_16x16x32_bf16(a, b2, acc2, 0, 0, 0);
        acc3 = __builtin_amdgcn_mfma_f32_16x16x32_bf16(a, b3, acc3, 0, 0, 0);
    }
    // C/D layout: col = lane&15, row = (lane>>4)*4 + reg
    float* dst = part + (size_t)kz * (B * NCLS);
    int rb = bb * 64 + wv * 16 + quad * 4;
#pragma unroll
    for (int ct = 0; ct < 4; ++ct) {
        f32x4 a = ct == 0 ? acc0 : ct == 1 ? acc1 : ct == 2 ? acc2 : acc3;
        int c = cb * 64 + ct * 16 + m;
        if (c < NCLS) {
#pragma unroll
            for (int r = 0; r < 4; ++r)
                dst[(size_t)(rb + r) * NCLS + c] = a[r];
        }
    }
}

__global__ __launch_bounds__(256) void k_reduce(
    const float* __restrict__ part, const float* __restrict__ b_cls,
    float* __restrict__ out)
{
    int i = blockIdx.x * 256 + threadIdx.x;          // B*NCLS = 256000
    float s = b_cls[i % NCLS];
#pragma unroll
    for (int z = 0; z < 4; ++z) s += part[(size_t)z * (B * NCLS) + i];
    out[i] = s;
}

extern "C" void kernel_launch(void* const* d_in, const int* in_sizes, int n_in,
                              void* d_out, int out_size, void* d_ws, size_t ws_size,
                              hipStream_t stream) {
    const float* x      = (const float*)d_in[0];
    const float* w_ret  = (const float*)d_in[1];
    const float* b_ret  = (const float*)d_in[2];
    const float* w_lgn  = (const float*)d_in[3];
    const float* b_lgn  = (const float*)d_in[4];
    const float* w_v1   = (const float*)d_in[5];
    const float* b_v1   = (const float*)d_in[6];
    const float* w_it   = (const float*)d_in[7];
    const float* b_it   = (const float*)d_in[8];
    const float* W_cls  = (const float*)d_in[9];
    const float* b_cls  = (const float*)d_in[10];
    const int*   pixmap = (const int*)d_in[11];
    const int*   m1     = (const int*)d_in[12];
    const int*   m2     = (const int*)d_in[13];
    float* out = (float*)d_out;

    char* w = (char*)d_ws;
    float*    r2t  = (float*)(w);                    // [3072][256] f32   3,145,728 B
    float*    r3t  = (float*)(w +  3145728);         // [6144][256] f32   6,291,456 B
    ushort_t* r4bt = (ushort_t*)(w +  9437184);      // [3072][256] bf16  1,572,864 B
    ushort_t* r4b  = (ushort_t*)(w + 11010048);      // [256][3072] bf16  1,572,864 B
    ushort_t* wbf  = (ushort_t*)(w + 12582912);      // [1024][3072] bf16 6,291,456 B
    float*    part = (float*)(w + 18874368);         // [4][256][1000]    4,096,000 B
                                                     // total 22,970,368 B

    k_retina_t<<<dim3(NRET / 32, B / 32), 256, 0, stream>>>(
        x, w_ret, b_ret, w_lgn, b_lgn, pixmap, r2t);
    k_sparse<NRET, false><<<NV1 / 4, 256, 0, stream>>>(r2t, m1, w_v1, b_v1, r3t);
    k_sparse<NV1, true><<<NIT / 4, 256, 0, stream>>>(r3t, m2, w_it, b_it, r4bt);
    k_prep<<<2304, 256, 0, stream>>>(W_cls, r4bt, wbf, r4b);
    k_cls_mfma<<<dim3(16, 4, 4), 256, 0, stream>>>(r4b, wbf, part);
    k_reduce<<<(B * NCLS) / 256, 256, 0, stream>>>(part, b_cls, out);
}

// Round 4
// 287.554 us; speedup vs baseline: 1.1614x; 1.0499x over previous
//
#include <hip/hip_runtime.h>

#define B     256
#define NPIX  49152
#define NRET  3072
#define NV1   6144
#define NIT   3072
#define NCLS  1000

typedef unsigned short ushort_t;
typedef __bf16 bf16x8 __attribute__((ext_vector_type(8)));
typedef float  f32x4  __attribute__((ext_vector_type(4)));
typedef int    i32x4  __attribute__((ext_vector_type(4)));

__device__ __forceinline__ float sigmoidf_(float v) {
    return 1.0f / (1.0f + __expf(-v));
}

__device__ __forceinline__ ushort_t f2bf(float f) {
    union { float f; unsigned u; } v; v.f = f;
    unsigned r = (v.u + 0x7fffu + ((v.u >> 16) & 1u)) >> 16;
    return (ushort_t)r;
}

// ---------------- Retina + LGN fused, writes TRANSPOSED [NRET][B] ----------------
__global__ __launch_bounds__(256) void k_retina_t(
    const float* __restrict__ x, const float* __restrict__ w_ret,
    const float* __restrict__ b_ret, const float* __restrict__ w_lgn,
    const float* __restrict__ b_lgn, const int* __restrict__ pixel_map,
    float* __restrict__ r2t)
{
    __shared__ float tile[32][33];
    int tx = threadIdx.x & 31, ty = threadIdx.x >> 5;
    int n0 = blockIdx.x * 32, b0 = blockIdx.y * 32;
    int n = n0 + tx;
    const int4*   pm4 = (const int4*)(pixel_map + n * 16);
    const float4* wr4 = (const float4*)(w_ret + n * 16);
    const float4* wl4 = (const float4*)(w_lgn + n * 16);
    int4 p[4]; float4 wr[4]; float slw = 0.f;
#pragma unroll
    for (int q = 0; q < 4; ++q) {
        p[q] = pm4[q]; wr[q] = wr4[q];
        float4 L = wl4[q]; slw += L.x + L.y + L.z + L.w;
    }
    float br = b_ret[n], bl = b_lgn[n];
#pragma unroll
    for (int i = 0; i < 4; ++i) {
        int b = b0 + ty + i * 8;
        const float* xb = x + (size_t)b * NPIX;
        float dot = 0.f;
#pragma unroll
        for (int q = 0; q < 4; ++q)
            dot += xb[p[q].x] * wr[q].x + xb[p[q].y] * wr[q].y
                 + xb[p[q].z] * wr[q].z + xb[p[q].w] * wr[q].w;
        float r1 = sigmoidf_(dot - br);
        tile[ty + i * 8][tx] = sigmoidf_(r1 * slw - bl);
    }
    __syncthreads();
#pragma unroll
    for (int i = 0; i < 4; ++i)
        r2t[(size_t)(n0 + ty + i * 8) * B + b0 + tx] = tile[tx][ty + i * 8];
}

// ---------------- Sparse mean layer: ONE WAVE per neuron ----------------
// Ballot+mbcnt compaction (no atomics), gather unrolled x4 (4 loads in flight).
template<int K, bool OUT_BF16>
__global__ __launch_bounds__(256) void k_sparse(
    const float* __restrict__ act_t,   // [K][B]
    const int*   __restrict__ mask,    // [NJ][K]
    const float* __restrict__ w,       // [NJ][32]
    const float* __restrict__ bias,    // [NJ]
    void*        __restrict__ out_t)   // [NJ][B] f32 or bf16
{
    constexpr int MAXI = 192;
    __shared__ int idxs[4][MAXI];
    int t = threadIdx.x, wv = t >> 6, l = t & 63;
    int j = blockIdx.x * 4 + wv;

    const i32x4* row4 = (const i32x4*)(mask + (size_t)j * K);
    int cnt = 0;                                   // wave-uniform (SGPR)
#pragma unroll
    for (int it = 0; it < K / 256; ++it) {         // K/4 int4 across 64 lanes
        int q = it * 64 + l;
        i32x4 m = __builtin_nontemporal_load(&row4[q]);
        int base = q * 4;
#pragma unroll
        for (int f = 0; f < 4; ++f) {
            int mv = m[f];
            unsigned long long bal = __ballot(mv != 0);
            int pre = __builtin_amdgcn_mbcnt_hi((unsigned)(bal >> 32),
                      __builtin_amdgcn_mbcnt_lo((unsigned)bal, 0));
            int slot = cnt + pre;
            if (mv && slot < MAXI) idxs[wv][slot] = base + f;
            cnt += __popcll(bal);
        }
    }
    int n = cnt < MAXI ? cnt : MAXI;

    const float4* a4 = (const float4*)act_t;       // [K][64] float4 view
    float4 acc0 = {0,0,0,0}, acc1 = {0,0,0,0}, acc2 = {0,0,0,0}, acc3 = {0,0,0,0};
    int i = 0;
    for (; i + 4 <= n; i += 4) {
        int j0 = idxs[wv][i], j1 = idxs[wv][i + 1];
        int j2 = idxs[wv][i + 2], j3 = idxs[wv][i + 3];
        float4 v0 = a4[(size_t)j0 * 64 + l];
        float4 v1 = a4[(size_t)j1 * 64 + l];
        float4 v2 = a4[(size_t)j2 * 64 + l];
        float4 v3 = a4[(size_t)j3 * 64 + l];
        acc0.x += v0.x; acc0.y += v0.y; acc0.z += v0.z; acc0.w += v0.w;
        acc1.x += v1.x; acc1.y += v1.y; acc1.z += v1.z; acc1.w += v1.w;
        acc2.x += v2.x; acc2.y += v2.y; acc2.z += v2.z; acc2.w += v2.w;
        acc3.x += v3.x; acc3.y += v3.y; acc3.z += v3.z; acc3.w += v3.w;
    }
    for (; i < n; ++i) {
        float4 v0 = a4[(size_t)idxs[wv][i] * 64 + l];
        acc0.x += v0.x; acc0.y += v0.y; acc0.z += v0.z; acc0.w += v0.w;
    }
    acc0.x += acc1.x + acc2.x + acc3.x;
    acc0.y += acc1.y + acc2.y + acc3.y;
    acc0.z += acc1.z + acc2.z + acc3.z;
    acc0.w += acc1.w + acc2.w + acc3.w;

    float sw = w[(size_t)j * 32 + (l & 31)];
#pragma unroll
    for (int off = 1; off < 32; off <<= 1) sw += __shfl_xor(sw, off);

    float bj = bias[j];
    float scale = sw / (float)n;
    float o0 = sigmoidf_(acc0.x * scale - bj);
    float o1 = sigmoidf_(acc0.y * scale - bj);
    float o2 = sigmoidf_(acc0.z * scale - bj);
    float o3 = sigmoidf_(acc0.w * scale - bj);

    if (OUT_BF16) {
        ushort_t* dst = (ushort_t*)out_t + (size_t)j * B + l * 4;
        ushort4 o; o.x = f2bf(o0); o.y = f2bf(o1); o.z = f2bf(o2); o.w = f2bf(o3);
        *(ushort4*)dst = o;
    } else {
        float4* dst = (float4*)((float*)out_t + (size_t)j * B + l * 4);
        float4 o; o.x = o0; o.y = o1; o.z = o2; o.w = o3;
        *dst = o;
    }
}

// ---------------- Prep: W_cls fp32 -> bf16 (padded to 1024 rows) + r4 transpose ----
__global__ __launch_bounds__(256) void k_prep(
    const float* __restrict__ W,           // [1000][3072]
    const ushort_t* __restrict__ r4bt,     // [NIT][B] bf16
    ushort_t* __restrict__ wbf,            // [1024][3072] bf16, rows>=1000 zero
    ushort_t* __restrict__ r4b)            // [B][NIT] bf16
{
    __shared__ ushort_t stile[32][33];
    int bx = blockIdx.x, t = threadIdx.x;
    if (bx < 1536) {
        int e = (bx * 256 + t) * 8;        // flat over 1024*3072
        uint4 o = {0, 0, 0, 0};
        if (e < NCLS * NIT) {
            float4 f0 = *(const float4*)(W + e);
            float4 f1 = *(const float4*)(W + e + 4);
            o.x = (unsigned)f2bf(f0.x) | ((unsigned)f2bf(f0.y) << 16);
            o.y = (unsigned)f2bf(f0.z) | ((unsigned)f2bf(f0.w) << 16);
            o.z = (unsigned)f2bf(f1.x) | ((unsigned)f2bf(f1.y) << 16);
            o.w = (unsigned)f2bf(f1.z) | ((unsigned)f2bf(f1.w) << 16);
        }
        *(uint4*)(wbf + e) = o;
    } else {
        int tb = bx - 1536;                // 96 n-tiles x 8 b-tiles
        int tn = tb / 8, tbb = tb % 8;
        int tx = t & 31, ty = t >> 5;
#pragma unroll
        for (int i = 0; i < 4; ++i)
            stile[ty + i * 8][tx] = r4bt[(size_t)(tn * 32 + ty + i * 8) * B + tbb * 32 + tx];
        __syncthreads();
#pragma unroll
        for (int i = 0; i < 4; ++i)
            r4b[(size_t)(tbb * 32 + ty + i * 8) * NIT + tn * 32 + tx] = stile[tx][ty + i * 8];
    }
}

// ---------------- Classifier: bf16 MFMA, split-K=4, fp32 partials ----------------
__global__ __launch_bounds__(256) void k_cls_mfma(
    const ushort_t* __restrict__ r4b,   // [256][3072] bf16
    const ushort_t* __restrict__ wbf,   // [1024][3072] bf16
    float* __restrict__ part)           // [4][256][1000]
{
    int t = threadIdx.x, wv = t >> 6, l = t & 63;
    int cb = blockIdx.x, bb = blockIdx.y, kz = blockIdx.z;
    int m = l & 15, quad = l >> 4;
    int brow = bb * 64 + wv * 16 + m;
    const bf16x8* pa = (const bf16x8*)(r4b + (size_t)brow * NIT + kz * 768 + quad * 8);
    const bf16x8* pb0 = (const bf16x8*)(wbf + (size_t)(cb * 64 +  0 + m) * NIT + kz * 768 + quad * 8);
    const bf16x8* pb1 = (const bf16x8*)(wbf + (size_t)(cb * 64 + 16 + m) * NIT + kz * 768 + quad * 8);
    const bf16x8* pb2 = (const bf16x8*)(wbf + (size_t)(cb * 64 + 32 + m) * NIT + kz * 768 + quad * 8);
    const bf16x8* pb3 = (const bf16x8*)(wbf + (size_t)(cb * 64 + 48 + m) * NIT + kz * 768 + quad * 8);

    f32x4 acc0 = {0,0,0,0}, acc1 = {0,0,0,0}, acc2 = {0,0,0,0}, acc3 = {0,0,0,0};
#pragma unroll 4
    for (int s = 0; s < 24; ++s) {      // 24 steps x 32 k = 768
        bf16x8 a  = pa [s * 4];
        bf16x8 b0 = pb0[s * 4];
        bf16x8 b1 = pb1[s * 4];
        bf16x8 b2 = pb2[s * 4];
        bf16x8 b3 = pb3[s * 4];
        acc0 = __builtin_amdgcn_mfma_f32_16x16x32_bf16(a, b0, acc0, 0, 0, 0);
        acc1 = __builtin_amdgcn_mfma_f32_16x16x32_bf16(a, b1, acc1, 0, 0, 0);
        acc2 = __builtin_amdgcn_mfma_f32_16x16x32_bf16(a, b2, acc2, 0, 0, 0);
        acc3 = __builtin_amdgcn_mfma_f32_16x16x32_bf16(a, b3, acc3, 0, 0, 0);
    }
    // C/D layout: col = lane&15, row = (lane>>4)*4 + reg
    float* dst = part + (size_t)kz * (B * NCLS);
    int rb = bb * 64 + wv * 16 + quad * 4;
#pragma unroll
    for (int ct = 0; ct < 4; ++ct) {
        f32x4 a = ct == 0 ? acc0 : ct == 1 ? acc1 : ct == 2 ? acc2 : acc3;
        int c = cb * 64 + ct * 16 + m;
        if (c < NCLS) {
#pragma unroll
            for (int r = 0; r < 4; ++r)
                dst[(size_t)(rb + r) * NCLS + c] = a[r];
        }
    }
}

__global__ __launch_bounds__(256) void k_reduce(
    const float* __restrict__ part, const float* __restrict__ b_cls,
    float* __restrict__ out)
{
    int i = blockIdx.x * 256 + threadIdx.x;          // B*NCLS = 256000
    float s = b_cls[i % NCLS];
#pragma unroll
    for (int z = 0; z < 4; ++z) s += part[(size_t)z * (B * NCLS) + i];
    out[i] = s;
}

extern "C" void kernel_launch(void* const* d_in, const int* in_sizes, int n_in,
                              void* d_out, int out_size, void* d_ws, size_t ws_size,
                              hipStream_t stream) {
    const float* x      = (const float*)d_in[0];
    const float* w_ret  = (const float*)d_in[1];
    const float* b_ret  = (const float*)d_in[2];
    const float* w_lgn  = (const float*)d_in[3];
    const float* b_lgn  = (const float*)d_in[4];
    const float* w_v1   = (const float*)d_in[5];
    const float* b_v1   = (const float*)d_in[6];
    const float* w_it   = (const float*)d_in[7];
    const float* b_it   = (const float*)d_in[8];
    const float* W_cls  = (const float*)d_in[9];
    const float* b_cls  = (const float*)d_in[10];
    const int*   pixmap = (const int*)d_in[11];
    const int*   m1     = (const int*)d_in[12];
    const int*   m2     = (const int*)d_in[13];
    float* out = (float*)d_out;

    char* w = (char*)d_ws;
    float*    r2t  = (float*)(w);                    // [3072][256] f32   3,145,728 B
    float*    r3t  = (float*)(w +  3145728);         // [6144][256] f32   6,291,456 B
    ushort_t* r4bt = (ushort_t*)(w +  9437184);      // [3072][256] bf16  1,572,864 B
    ushort_t* r4b  = (ushort_t*)(w + 11010048);      // [256][3072] bf16  1,572,864 B
    ushort_t* wbf  = (ushort_t*)(w + 12582912);      // [1024][3072] bf16 6,291,456 B
    float*    part = (float*)(w + 18874368);         // [4][256][1000]    4,096,000 B

    k_retina_t<<<dim3(NRET / 32, B / 32), 256, 0, stream>>>(
        x, w_ret, b_ret, w_lgn, b_lgn, pixmap, r2t);
    k_sparse<NRET, false><<<NV1 / 4, 256, 0, stream>>>(r2t, m1, w_v1, b_v1, r3t);
    k_sparse<NV1, true><<<NIT / 4, 256, 0, stream>>>(r3t, m2, w_it, b_it, r4bt);
    k_prep<<<2304, 256, 0, stream>>>(W_cls, r4bt, wbf, r4b);
    k_cls_mfma<<<dim3(16, 4, 4), 256, 0, stream>>>(r4b, wbf, part);
    k_reduce<<<(B * NCLS) / 256, 256, 0, stream>>>(part, b_cls, out);
}

// Round 5
// 276.529 us; speedup vs baseline: 1.2077x; 1.0399x over previous
//
#include <hip/hip_runtime.h>

#define B     256
#define NPIX  49152
#define NRET  3072
#define NV1   6144
#define NIT   3072
#define NCLS  1000

typedef unsigned short ushort_t;
typedef __bf16 bf16x8 __attribute__((ext_vector_type(8)));
typedef float  f32x4  __attribute__((ext_vector_type(4)));
typedef int    i32x4  __attribute__((ext_vector_type(4)));

__device__ __forceinline__ float sigmoidf_(float v) {
    return 1.0f / (1.0f + __expf(-v));
}

__device__ __forceinline__ ushort_t f2bf(float f) {
    union { float f; unsigned u; } v; v.f = f;
    unsigned r = (v.u + 0x7fffu + ((v.u >> 16) & 1u)) >> 16;
    return (ushort_t)r;
}

// unpack uint4 (8 bf16) and accumulate into acc[8] (fp32)
__device__ __forceinline__ void bfacc(uint4 v, float* acc) {
    unsigned u0 = v.x, u1 = v.y, u2 = v.z, u3 = v.w;
    acc[0] += __uint_as_float(u0 << 16);
    acc[1] += __uint_as_float(u0 & 0xffff0000u);
    acc[2] += __uint_as_float(u1 << 16);
    acc[3] += __uint_as_float(u1 & 0xffff0000u);
    acc[4] += __uint_as_float(u2 << 16);
    acc[5] += __uint_as_float(u2 & 0xffff0000u);
    acc[6] += __uint_as_float(u3 << 16);
    acc[7] += __uint_as_float(u3 & 0xffff0000u);
}

// ---------------- Retina + LGN fused, writes TRANSPOSED bf16 [NRET][B] ----------------
__global__ __launch_bounds__(256) void k_retina_t(
    const float* __restrict__ x, const float* __restrict__ w_ret,
    const float* __restrict__ b_ret, const float* __restrict__ w_lgn,
    const float* __restrict__ b_lgn, const int* __restrict__ pixel_map,
    ushort_t* __restrict__ r2t)
{
    __shared__ ushort_t tile[32][33];
    int tx = threadIdx.x & 31, ty = threadIdx.x >> 5;
    int n0 = blockIdx.x * 32, b0 = blockIdx.y * 32;
    int n = n0 + tx;
    const int4*   pm4 = (const int4*)(pixel_map + n * 16);
    const float4* wr4 = (const float4*)(w_ret + n * 16);
    const float4* wl4 = (const float4*)(w_lgn + n * 16);
    int4 p[4]; float4 wr[4]; float slw = 0.f;
#pragma unroll
    for (int q = 0; q < 4; ++q) {
        p[q] = pm4[q]; wr[q] = wr4[q];
        float4 L = wl4[q]; slw += L.x + L.y + L.z + L.w;
    }
    float br = b_ret[n], bl = b_lgn[n];
#pragma unroll
    for (int i = 0; i < 4; ++i) {
        int b = b0 + ty + i * 8;
        const float* xb = x + (size_t)b * NPIX;
        float dot = 0.f;
#pragma unroll
        for (int q = 0; q < 4; ++q)
            dot += xb[p[q].x] * wr[q].x + xb[p[q].y] * wr[q].y
                 + xb[p[q].z] * wr[q].z + xb[p[q].w] * wr[q].w;
        float r1 = sigmoidf_(dot - br);
        tile[ty + i * 8][tx] = f2bf(sigmoidf_(r1 * slw - bl));
    }
    __syncthreads();
#pragma unroll
    for (int i = 0; i < 4; ++i)
        r2t[(size_t)(n0 + ty + i * 8) * B + b0 + tx] = tile[tx][ty + i * 8];
}

// ---------------- Sparse mean layer: one wave per neuron, bf16 act, 2 rows/load ----
// Scan: explicit load-all-then-ballot (12 int4 in flight). Gather: lanes 0-31 row i,
// lanes 32-63 row i+1 (bf16 row = 512B = 32 lanes x 16B); shfl_xor(32) merges.
template<int K>
__global__ __launch_bounds__(256) void k_sparse(
    const ushort_t* __restrict__ act_t,  // [K][B] bf16
    const int*      __restrict__ mask,   // [NJ][K]
    const float*    __restrict__ w,      // [NJ][32]
    const float*    __restrict__ bias,   // [NJ]
    ushort_t*       __restrict__ out_t)  // [NJ][B] bf16
{
    constexpr int MAXI = 192;
    __shared__ int idxs[4][MAXI];
    int t = threadIdx.x, wv = t >> 6, l = t & 63;
    int half = l >> 5, lb = l & 31;
    int j = blockIdx.x * 4 + wv;

    const i32x4* row4 = (const i32x4*)(mask + (size_t)j * K);
    int cnt = 0;                                   // wave-uniform (SGPR)
#pragma unroll
    for (int h = 0; h < K / 3072; ++h) {
        i32x4 mb[12];
#pragma unroll
        for (int it = 0; it < 12; ++it)
            mb[it] = __builtin_nontemporal_load(&row4[h * 768 + it * 64 + l]);
#pragma unroll
        for (int it = 0; it < 12; ++it) {
            int base = (h * 768 + it * 64 + l) * 4;
#pragma unroll
            for (int f = 0; f < 4; ++f) {
                int mv = mb[it][f];
                unsigned long long bal = __ballot(mv != 0);
                int pre = __builtin_amdgcn_mbcnt_hi((unsigned)(bal >> 32),
                          __builtin_amdgcn_mbcnt_lo((unsigned)bal, 0));
                int slot = cnt + pre;
                if (mv && slot < MAXI) idxs[wv][slot] = base + f;
                cnt += __popcll(bal);
            }
        }
    }
    int n = cnt < MAXI ? cnt : MAXI;

    const uint4* a4 = (const uint4*)act_t;         // bf16 row = 32 uint4
    float acc[8] = {0,0,0,0,0,0,0,0};
    float acc2[8] = {0,0,0,0,0,0,0,0};
    int i = 0;
    int n4 = n & ~3;
    for (; i < n4; i += 4) {                       // 4 rows per iter (2 per load)
        int ja = idxs[wv][i + half];
        int jb = idxs[wv][i + 2 + half];
        uint4 va = a4[(size_t)ja * 32 + lb];
        uint4 vb = a4[(size_t)jb * 32 + lb];
        bfacc(va, acc);
        bfacc(vb, acc2);
    }
    if (i + 2 <= n) {
        uint4 va = a4[(size_t)idxs[wv][i + half] * 32 + lb];
        bfacc(va, acc);
        i += 2;
    }
    if (n & 1) {
        if (half == 0) {
            uint4 va = a4[(size_t)idxs[wv][n - 1] * 32 + lb];
            bfacc(va, acc);
        }
    }
#pragma unroll
    for (int k = 0; k < 8; ++k) acc[k] += acc2[k];
#pragma unroll
    for (int k = 0; k < 8; ++k) acc[k] += __shfl_xor(acc[k], 32);

    float sw = w[(size_t)j * 32 + (l & 31)];
#pragma unroll
    for (int off = 1; off < 32; off <<= 1) sw += __shfl_xor(sw, off);

    float bj = bias[j];
    float scale = sw / (float)n;
    if (half == 0) {
        uint4 o;
        unsigned r[8];
#pragma unroll
        for (int k = 0; k < 8; ++k)
            r[k] = f2bf(sigmoidf_(acc[k] * scale - bj));
        o.x = r[0] | (r[1] << 16);
        o.y = r[2] | (r[3] << 16);
        o.z = r[4] | (r[5] << 16);
        o.w = r[6] | (r[7] << 16);
        *(uint4*)(out_t + (size_t)j * B + lb * 8) = o;
    }
}

// ---------------- Prep: W_cls fp32 -> bf16 (padded to 1024 rows) + r4 transpose ----
__global__ __launch_bounds__(256) void k_prep(
    const float* __restrict__ W,           // [1000][3072]
    const ushort_t* __restrict__ r4bt,     // [NIT][B] bf16
    ushort_t* __restrict__ wbf,            // [1024][3072] bf16, rows>=1000 zero
    ushort_t* __restrict__ r4b)            // [B][NIT] bf16
{
    __shared__ ushort_t stile[32][33];
    int bx = blockIdx.x, t = threadIdx.x;
    if (bx < 1536) {
        int e = (bx * 256 + t) * 8;        // flat over 1024*3072
        uint4 o = {0, 0, 0, 0};
        if (e < NCLS * NIT) {
            float4 f0 = *(const float4*)(W + e);
            float4 f1 = *(const float4*)(W + e + 4);
            o.x = (unsigned)f2bf(f0.x) | ((unsigned)f2bf(f0.y) << 16);
            o.y = (unsigned)f2bf(f0.z) | ((unsigned)f2bf(f0.w) << 16);
            o.z = (unsigned)f2bf(f1.x) | ((unsigned)f2bf(f1.y) << 16);
            o.w = (unsigned)f2bf(f1.z) | ((unsigned)f2bf(f1.w) << 16);
        }
        *(uint4*)(wbf + e) = o;
    } else {
        int tb = bx - 1536;                // 96 n-tiles x 8 b-tiles
        int tn = tb / 8, tbb = tb % 8;
        int tx = t & 31, ty = t >> 5;
#pragma unroll
        for (int i = 0; i < 4; ++i)
            stile[ty + i * 8][tx] = r4bt[(size_t)(tn * 32 + ty + i * 8) * B + tbb * 32 + tx];
        __syncthreads();
#pragma unroll
        for (int i = 0; i < 4; ++i)
            r4b[(size_t)(tbb * 32 + ty + i * 8) * NIT + tn * 32 + tx] = stile[tx][ty + i * 8];
    }
}

// ---------------- Classifier: bf16 MFMA, split-K=4, fp32 partials ----------------
__global__ __launch_bounds__(256) void k_cls_mfma(
    const ushort_t* __restrict__ r4b,   // [256][3072] bf16
    const ushort_t* __restrict__ wbf,   // [1024][3072] bf16
    float* __restrict__ part)           // [4][256][1000]
{
    int t = threadIdx.x, wv = t >> 6, l = t & 63;
    int cb = blockIdx.x, bb = blockIdx.y, kz = blockIdx.z;
    int m = l & 15, quad = l >> 4;
    int brow = bb * 64 + wv * 16 + m;
    const bf16x8* pa = (const bf16x8*)(r4b + (size_t)brow * NIT + kz * 768 + quad * 8);
    const bf16x8* pb0 = (const bf16x8*)(wbf + (size_t)(cb * 64 +  0 + m) * NIT + kz * 768 + quad * 8);
    const bf16x8* pb1 = (const bf16x8*)(wbf + (size_t)(cb * 64 + 16 + m) * NIT + kz * 768 + quad * 8);
    const bf16x8* pb2 = (const bf16x8*)(wbf + (size_t)(cb * 64 + 32 + m) * NIT + kz * 768 + quad * 8);
    const bf16x8* pb3 = (const bf16x8*)(wbf + (size_t)(cb * 64 + 48 + m) * NIT + kz * 768 + quad * 8);

    f32x4 acc0 = {0,0,0,0}, acc1 = {0,0,0,0}, acc2 = {0,0,0,0}, acc3 = {0,0,0,0};
#pragma unroll 4
    for (int s = 0; s < 24; ++s) {      // 24 steps x 32 k = 768
        bf16x8 a  = pa [s * 4];
        bf16x8 b0 = pb0[s * 4];
        bf16x8 b1 = pb1[s * 4];
        bf16x8 b2 = pb2[s * 4];
        bf16x8 b3 = pb3[s * 4];
        acc0 = __builtin_amdgcn_mfma_f32_16x16x32_bf16(a, b0, acc0, 0, 0, 0);
        acc1 = __builtin_amdgcn_mfma_f32_16x16x32_bf16(a, b1, acc1, 0, 0, 0);
        acc2 = __builtin_amdgcn_mfma_f32_16x16x32_bf16(a, b2, acc2, 0, 0, 0);
        acc3 = __builtin_amdgcn_mfma_f32_16x16x32_bf16(a, b3, acc3, 0, 0, 0);
    }
    // C/D layout: col = lane&15, row = (lane>>4)*4 + reg
    float* dst = part + (size_t)kz * (B * NCLS);
    int rb = bb * 64 + wv * 16 + quad * 4;
#pragma unroll
    for (int ct = 0; ct < 4; ++ct) {
        f32x4 a = ct == 0 ? acc0 : ct == 1 ? acc1 : ct == 2 ? acc2 : acc3;
        int c = cb * 64 + ct * 16 + m;
        if (c < NCLS) {
#pragma unroll
            for (int r = 0; r < 4; ++r)
                dst[(size_t)(rb + r) * NCLS + c] = a[r];
        }
    }
}

__global__ __launch_bounds__(256) void k_reduce(
    const float* __restrict__ part, const float* __restrict__ b_cls,
    float* __restrict__ out)
{
    int i = blockIdx.x * 256 + threadIdx.x;          // B*NCLS = 256000
    float s = b_cls[i % NCLS];
#pragma unroll
    for (int z = 0; z < 4; ++z) s += part[(size_t)z * (B * NCLS) + i];
    out[i] = s;
}

extern "C" void kernel_launch(void* const* d_in, const int* in_sizes, int n_in,
                              void* d_out, int out_size, void* d_ws, size_t ws_size,
                              hipStream_t stream) {
    const float* x      = (const float*)d_in[0];
    const float* w_ret  = (const float*)d_in[1];
    const float* b_ret  = (const float*)d_in[2];
    const float* w_lgn  = (const float*)d_in[3];
    const float* b_lgn  = (const float*)d_in[4];
    const float* w_v1   = (const float*)d_in[5];
    const float* b_v1   = (const float*)d_in[6];
    const float* w_it   = (const float*)d_in[7];
    const float* b_it   = (const float*)d_in[8];
    const float* W_cls  = (const float*)d_in[9];
    const float* b_cls  = (const float*)d_in[10];
    const int*   pixmap = (const int*)d_in[11];
    const int*   m1     = (const int*)d_in[12];
    const int*   m2     = (const int*)d_in[13];
    float* out = (float*)d_out;

    char* w = (char*)d_ws;
    ushort_t* r2t  = (ushort_t*)(w);                 // [3072][256] bf16  1,572,864 B
    ushort_t* r3t  = (ushort_t*)(w +  1572864);      // [6144][256] bf16  3,145,728 B
    ushort_t* r4bt = (ushort_t*)(w +  4718592);      // [3072][256] bf16  1,572,864 B
    ushort_t* r4b  = (ushort_t*)(w +  6291456);      // [256][3072] bf16  1,572,864 B
    ushort_t* wbf  = (ushort_t*)(w +  7864320);      // [1024][3072] bf16 6,291,456 B
    float*    part = (float*)(w + 14155776);         // [4][256][1000]    4,096,000 B
                                                     // total 18,251,776 B

    k_retina_t<<<dim3(NRET / 32, B / 32), 256, 0, stream>>>(
        x, w_ret, b_ret, w_lgn, b_lgn, pixmap, r2t);
    k_sparse<NRET><<<NV1 / 4, 256, 0, stream>>>(r2t, m1, w_v1, b_v1, r3t);
    k_sparse<NV1><<<NIT / 4, 256, 0, stream>>>(r3t, m2, w_it, b_it, r4bt);
    k_prep<<<2304, 256, 0, stream>>>(W_cls, r4bt, wbf, r4b);
    k_cls_mfma<<<dim3(16, 4, 4), 256, 0, stream>>>(r4b, wbf, part);
    k_reduce<<<(B * NCLS) / 256, 256, 0, stream>>>(part, b_cls, out);
}